// Round 15
// baseline (409.317 us; speedup 1.0000x reference)
//
#include <hip/hip_runtime.h>
#include <hip/hip_bf16.h>

typedef __attribute__((ext_vector_type(8))) short short8;
typedef __attribute__((ext_vector_type(4))) float f32x4;
typedef __attribute__((ext_vector_type(16))) float f32x16;

#define B_SZ 4
#define T_SEQ 2048
#define C_DIM 2048
#define NH 16
#define NKV 4
#define HD 128

#define MFMA16 __builtin_amdgcn_mfma_f32_16x16x32_bf16
#define MFMA32 __builtin_amdgcn_mfma_f32_32x32x16_bf16

__device__ __forceinline__ unsigned short f2bf(float f) {
  union { __hip_bfloat16 h; unsigned short u; } v;
  v.h = __float2bfloat16(f);
  return v.u;
}
__device__ __forceinline__ float bf2f(unsigned short u) {
  union { unsigned short u; __hip_bfloat16 h; } v;
  v.u = u;
  return __bfloat162float(v.h);
}
__device__ __forceinline__ unsigned pkbf(float lo, float hi) {
  return (unsigned)f2bf(lo) | ((unsigned)f2bf(hi) << 16);
}

__device__ __forceinline__ void gload_lds16(const unsigned short* g, unsigned short* l) {
  __builtin_amdgcn_global_load_lds(
      (const __attribute__((address_space(1))) unsigned int*)g,
      (__attribute__((address_space(3))) unsigned int*)l, 16, 0, 0);
}

// ---------------- prep: cast x (bid < 16384) + all weight transposes (one launch) ----------
__global__ void prep(const float* __restrict__ x, unsigned short* __restrict__ xb,
                     const float* __restrict__ Wq, const float* __restrict__ Wk,
                     const float* __restrict__ Wv, const float* __restrict__ Wo,
                     unsigned short* __restrict__ WqkvT, unsigned short* __restrict__ WoT) {
  int bid = blockIdx.x, tid = threadIdx.x;
  if (bid < 16384) {
    int i = bid * 256 + tid;
    float4 f = ((const float4*)x)[i];
    ushort4 u = make_ushort4(f2bf(f.x), f2bf(f.y), f2bf(f.z), f2bf(f.w));
    ((ushort4*)xb)[i] = u;
    return;
  }
  __shared__ float tile[32][33];
  int idx = bid - 16384;        // 0..10239
  int y = idx >> 6, kx = idx & 63;
  const float* W;
  unsigned short* Wt;
  int N, n0;
  if (y < 64) { W = Wq; Wt = WqkvT; N = 2048; n0 = y * 32; }
  else if (y < 80) { W = Wk; Wt = WqkvT + (size_t)2048 * 2048; N = 512; n0 = (y - 64) * 32; }
  else if (y < 96) { W = Wv; Wt = WqkvT + (size_t)2560 * 2048; N = 512; n0 = (y - 80) * 32; }
  else { W = Wo; Wt = WoT; N = 2048; n0 = (y - 96) * 32; }
  int k0 = kx * 32;
  int tx = tid & 31, ty = tid >> 5;
#pragma unroll
  for (int i = 0; i < 4; i++)
    tile[ty + i * 8][tx] = W[(size_t)(k0 + ty + i * 8) * N + n0 + tx];
  __syncthreads();
#pragma unroll
  for (int i = 0; i < 4; i++)
    Wt[(size_t)(n0 + ty + i * 8) * 2048 + k0 + tx] = f2bf(tile[tx][ty + i * 8]);
}

// ------- fused qkv GEMM (128x256, 2-phase counted-vmcnt) + RoPE/RMSNorm/V-transpose -------
// grid 768 = 64 bx x 12 by. by<8: Q heads {2by,2by+1}; by 8-9: K heads; by 10-11: V heads.
// Epilogue reuses the 96KB staging LDS as a 128x266-stride bf16 tile (odd-dword stride ->
// conflict-free column reads), then applies ropevt's exact math in-block: RoPE pairs
// (d,d+64) and the 128-d RMSNorm never cross the 256-col tile. V written transposed
// (lane varies t -> contiguous). Numerics identical to the unfused path (acc->bf16->rope).
__global__ __launch_bounds__(512, 2) void gemm_qkv(const unsigned short* __restrict__ A,
                                                   const unsigned short* __restrict__ Bt,
                                                   const float* __restrict__ cosp,
                                                   const float* __restrict__ sinp,
                                                   unsigned short* __restrict__ Qb,
                                                   unsigned short* __restrict__ Kb,
                                                   unsigned short* __restrict__ Vt, int K,
                                                   int GX) {
  __shared__ alignas(16) unsigned short lds[2][3][128 * 64];  // 0=A, 1=B0, 2=B1
  const int tid = threadIdx.x, lane = tid & 63, wid = tid >> 6;
  const int wave_m = wid >> 2, wave_n = wid & 3;
  const int r16 = lane & 15, q4 = lane >> 4;
  const int sw = r16 & 7;

  int nwg = gridDim.x, orig = blockIdx.x;
  int qq = nwg >> 3, rr = nwg & 7;
  int xcd = orig & 7, loc = orig >> 3;
  int wg = (xcd < rr ? xcd * (qq + 1) : rr * (qq + 1) + (xcd - rr) * qq) + loc;
  int bx = wg % GX, by = wg / GX;
  const size_t row0 = (size_t)bx * 128, col0 = (size_t)by * 256;

  const unsigned short* Ab = A + row0 * K;
  const unsigned short* Bb0 = Bt + col0 * K;
  const unsigned short* Bb1 = Bt + (col0 + 128) * K;

  const int srow = lane >> 3, spb = lane & 7;
  auto stage = [&](const unsigned short* base, int buf, int slot, int k0) {
#pragma unroll
    for (int j = 0; j < 2; ++j) {
      int cw = j * 8 + wid;
      int row = cw * 8 + srow;
      gload_lds16(base + (size_t)row * K + k0 + ((spb ^ srow) * 8), &lds[buf][slot][cw * 512]);
    }
  };

  f32x4 acc[4][4];
  f32x4 zero = {0.f, 0.f, 0.f, 0.f};
#pragma unroll
  for (int m = 0; m < 4; m++)
#pragma unroll
    for (int n = 0; n < 4; n++) acc[m][n] = zero;

  const int NT = K / 64;
  stage(Ab, 0, 0, 0);
  stage(Bb0, 0, 1, 0);
  stage(Bb1, 0, 2, 0);
  stage(Ab, 1, 0, 64);
  asm volatile("s_waitcnt vmcnt(2)" ::: "memory");
  __builtin_amdgcn_s_barrier();

  short8 af[4][2], b01[2][2], b23[2][2];
  const int bslot = 1 + (wave_n >> 1);
  const int bro = (wave_n & 1) * 64;

  int cur = 0;
#pragma unroll 1
  for (int t = 0; t < NT; ++t) {
    const unsigned short* Ah = &lds[cur][0][0];
    const unsigned short* Bh = &lds[cur][bslot][0];
    const int k1 = t * 64 + 64, k2 = t * 64 + 128;
#pragma unroll
    for (int mf = 0; mf < 4; mf++)
#pragma unroll
      for (int kk = 0; kk < 2; kk++)
        af[mf][kk] =
            *(const short8*)(Ah + (wave_m * 64 + mf * 16 + r16) * 64 + (((kk * 4 + q4) ^ sw) * 8));
#pragma unroll
    for (int nf = 0; nf < 2; nf++)
#pragma unroll
      for (int kk = 0; kk < 2; kk++)
        b01[nf][kk] =
            *(const short8*)(Bh + (bro + nf * 16 + r16) * 64 + (((kk * 4 + q4) ^ sw) * 8));
    if (t + 1 < NT) stage(Bb0, cur ^ 1, 1, k1);
    __builtin_amdgcn_s_barrier();
    asm volatile("s_waitcnt lgkmcnt(0)" ::: "memory");
    __builtin_amdgcn_s_setprio(1);
#pragma unroll
    for (int mf = 0; mf < 4; mf++)
#pragma unroll
      for (int nf = 0; nf < 2; nf++)
#pragma unroll
        for (int kk = 0; kk < 2; kk++)
          acc[mf][nf] = MFMA16(af[mf][kk], b01[nf][kk], acc[mf][nf], 0, 0, 0);
    __builtin_amdgcn_s_setprio(0);
    __builtin_amdgcn_s_barrier();
#pragma unroll
    for (int nf = 0; nf < 2; nf++)
#pragma unroll
      for (int kk = 0; kk < 2; kk++)
        b23[nf][kk] =
            *(const short8*)(Bh + (bro + (nf + 2) * 16 + r16) * 64 + (((kk * 4 + q4) ^ sw) * 8));
    if (t + 1 < NT) stage(Bb1, cur ^ 1, 2, k1);
    if (t + 2 < NT) stage(Ab, cur, 0, k2);
    __builtin_amdgcn_s_barrier();
    asm volatile("s_waitcnt lgkmcnt(0)" ::: "memory");
    __builtin_amdgcn_s_setprio(1);
#pragma unroll
    for (int mf = 0; mf < 4; mf++)
#pragma unroll
      for (int nf = 0; nf < 2; nf++)
#pragma unroll
        for (int kk = 0; kk < 2; kk++)
          acc[mf][nf + 2] = MFMA16(af[mf][kk], b23[nf][kk], acc[mf][nf + 2], 0, 0, 0);
    __builtin_amdgcn_s_setprio(0);
    if (t + 2 < NT)
      asm volatile("s_waitcnt vmcnt(2)" ::: "memory");
    else if (t + 1 < NT)
      asm volatile("s_waitcnt vmcnt(0)" ::: "memory");
    __builtin_amdgcn_s_barrier();
    cur ^= 1;
  }

  // ---- fused epilogue ----
  unsigned short* Tl = (unsigned short*)&lds[0][0][0];
  const int TS = 266;  // odd-dword stride: conflict-free column access
#pragma unroll
  for (int mf = 0; mf < 4; mf++)
#pragma unroll
    for (int nf = 0; nf < 4; nf++) {
      int rb = wave_m * 64 + mf * 16 + q4 * 4;
      int ccl = wave_n * 64 + nf * 16 + r16;
#pragma unroll
      for (int jj = 0; jj < 4; jj++) Tl[(rb + jj) * TS + ccl] = f2bf(acc[mf][nf][jj]);
    }
  __syncthreads();

  const int t0g = (int)(row0 % T_SEQ);
  const int bb = (int)(row0 / T_SEQ);
  if (by < 10) {
    // RoPE + RMSNorm: 256 (t,head) tasks, 32 per wave
    const float oscale = (by < 8) ? 0.08838834764831845f : 1.0f;
#pragma unroll 1
    for (int it = 0; it < 32; ++it) {
      int task = wid * 32 + it;
      int tloc = task & 127, hl = task >> 7;
      int t = t0g + tloc;
      float x1 = bf2f(Tl[tloc * TS + hl * 128 + lane]);
      float x2 = bf2f(Tl[tloc * TS + hl * 128 + 64 + lane]);
      float c = cosp[t * 64 + lane], s = sinp[t * 64 + lane];
      float y1 = x1 * c + x2 * s;
      float y2 = x2 * c - x1 * s;
      float ss2 = y1 * y1 + y2 * y2;
#pragma unroll
      for (int d = 1; d < 64; d <<= 1) ss2 += __shfl_xor(ss2, d);
      float r = rsqrtf(ss2 * (1.f / 128.f) + 1e-6f) * oscale;
      unsigned short* dst;
      if (by < 8) {
        int hq = 2 * by + hl;
        dst = Qb + ((size_t)(bb * NH + hq) * T_SEQ + t) * HD;
      } else {
        int kvh = 2 * (by - 8) + hl;
        dst = Kb + ((size_t)(bb * NKV + kvh) * T_SEQ + t) * HD;
      }
      dst[lane] = f2bf(y1 * r);
      dst[64 + lane] = f2bf(y2 * r);
    }
  } else {
    // V transpose: 256 cols x 2 t-chunks = 512 tasks, 64 per wave; lane varies t -> coalesced
#pragma unroll 1
    for (int it = 0; it < 64; ++it) {
      int task = wid * 64 + it;
      int col = task & 255, ch = task >> 8;
      int tloc = ch * 64 + lane;
      int hl = col >> 7, d = col & 127;
      int kvh = 2 * (by - 10) + hl;
      Vt[((size_t)(bb * NKV + kvh) * HD + d) * T_SEQ + t0g + tloc] = Tl[tloc * TS + col];
    }
  }
}

// ---------------- 256x256 8-phase GEMM (out-proj: 256 blocks = 1.0 round) ----------------
template <typename OutT>
__global__ __launch_bounds__(512, 2) void gemm256(const unsigned short* __restrict__ A,
                                                  const unsigned short* __restrict__ Bt,
                                                  OutT* __restrict__ Cc, int N, int K, int GX) {
  __shared__ alignas(16) unsigned short lds[2][4][128 * 64];
  const int tid = threadIdx.x, lane = tid & 63, wid = tid >> 6;
  const int wave_m = wid >> 2, wave_n = wid & 3;
  const int r16 = lane & 15, q4 = lane >> 4;
  const int sw = r16 & 7;

  int nwg = gridDim.x, orig = blockIdx.x;
  int qq = nwg >> 3, rr = nwg & 7;
  int xcd = orig & 7, loc = orig >> 3;
  int wg = (xcd < rr ? xcd * (qq + 1) : rr * (qq + 1) + (xcd - rr) * qq) + loc;
  int bx = wg % GX, by = wg / GX;
  const size_t row0 = (size_t)bx * 256, col0 = (size_t)by * 256;

  const unsigned short* Ab0 = A + row0 * K;
  const unsigned short* Ab1 = A + (row0 + 128) * K;
  const unsigned short* Bb0 = Bt + col0 * K;
  const unsigned short* Bb1 = Bt + (col0 + 128) * K;

  const int srow = lane >> 3, spb = lane & 7;
  auto stage = [&](const unsigned short* base, int buf, int slot, int k0) {
#pragma unroll
    for (int j = 0; j < 2; ++j) {
      int cw = j * 8 + wid;
      int row = cw * 8 + srow;
      gload_lds16(base + (size_t)row * K + k0 + ((spb ^ srow) * 8), &lds[buf][slot][cw * 512]);
    }
  };

  f32x4 acc[8][4];
  f32x4 zero = {0.f, 0.f, 0.f, 0.f};
#pragma unroll
  for (int m = 0; m < 8; m++)
#pragma unroll
    for (int n = 0; n < 4; n++) acc[m][n] = zero;

  const int NT = K / 64;
  stage(Ab0, 0, 0, 0);
  stage(Ab1, 0, 1, 0);
  stage(Bb0, 0, 2, 0);
  stage(Bb1, 0, 3, 0);
  stage(Ab0, 1, 0, 64);
  stage(Ab1, 1, 1, 64);
  asm volatile("s_waitcnt vmcnt(4)" ::: "memory");
  __builtin_amdgcn_s_barrier();

  short8 af[4][2], b01[2][2], b23[2][2];
  const int bslot = 2 + (wave_n >> 1);
  const int bro = (wave_n & 1) * 64;

  int cur = 0;
#pragma unroll 1
  for (int t = 0; t < NT; ++t) {
    const unsigned short* Ah = &lds[cur][wave_m][0];
    const unsigned short* Bh = &lds[cur][bslot][0];
    const int k1 = t * 64 + 64, k2 = t * 64 + 128;
#pragma unroll
    for (int mf = 0; mf < 4; mf++)
#pragma unroll
      for (int kk = 0; kk < 2; kk++)
        af[mf][kk] = *(const short8*)(Ah + (mf * 16 + r16) * 64 + (((kk * 4 + q4) ^ sw) * 8));
#pragma unroll
    for (int nf = 0; nf < 2; nf++)
#pragma unroll
      for (int kk = 0; kk < 2; kk++)
        b01[nf][kk] =
            *(const short8*)(Bh + (bro + nf * 16 + r16) * 64 + (((kk * 4 + q4) ^ sw) * 8));
    if (t + 1 < NT) stage(Bb0, cur ^ 1, 2, k1);
    __builtin_amdgcn_s_barrier();
    asm volatile("s_waitcnt lgkmcnt(0)" ::: "memory");
    __builtin_amdgcn_s_setprio(1);
#pragma unroll
    for (int mf = 0; mf < 4; mf++)
#pragma unroll
      for (int nf = 0; nf < 2; nf++)
#pragma unroll
        for (int kk = 0; kk < 2; kk++)
          acc[mf][nf] = MFMA16(af[mf][kk], b01[nf][kk], acc[mf][nf], 0, 0, 0);
    __builtin_amdgcn_s_setprio(0);
    __builtin_amdgcn_s_barrier();
#pragma unroll
    for (int nf = 0; nf < 2; nf++)
#pragma unroll
      for (int kk = 0; kk < 2; kk++)
        b23[nf][kk] =
            *(const short8*)(Bh + (bro + (nf + 2) * 16 + r16) * 64 + (((kk * 4 + q4) ^ sw) * 8));
    if (t + 1 < NT) stage(Bb1, cur ^ 1, 3, k1);
    __builtin_amdgcn_s_barrier();
    asm volatile("s_waitcnt lgkmcnt(0)" ::: "memory");
    __builtin_amdgcn_s_setprio(1);
#pragma unroll
    for (int mf = 0; mf < 4; mf++)
#pragma unroll
      for (int nf = 0; nf < 2; nf++)
#pragma unroll
        for (int kk = 0; kk < 2; kk++)
          acc[mf][nf + 2] = MFMA16(af[mf][kk], b23[nf][kk], acc[mf][nf + 2], 0, 0, 0);
    __builtin_amdgcn_s_setprio(0);
    __builtin_amdgcn_s_barrier();
#pragma unroll
    for (int mf = 0; mf < 4; mf++)
#pragma unroll
      for (int kk = 0; kk < 2; kk++)
        af[mf][kk] =
            *(const short8*)(Ah + ((mf + 4) * 16 + r16) * 64 + (((kk * 4 + q4) ^ sw) * 8));
    __builtin_amdgcn_s_barrier();
    asm volatile("s_waitcnt lgkmcnt(0)" ::: "memory");
    __builtin_amdgcn_s_setprio(1);
#pragma unroll
    for (int mf = 0; mf < 4; mf++)
#pragma unroll
      for (int nf = 0; nf < 2; nf++)
#pragma unroll
        for (int kk = 0; kk < 2; kk++)
          acc[mf + 4][nf] = MFMA16(af[mf][kk], b01[nf][kk], acc[mf + 4][nf], 0, 0, 0);
    __builtin_amdgcn_s_setprio(0);
    __builtin_amdgcn_s_barrier();
    if (t + 2 < NT) {
      stage(Ab0, cur, 0, k2);
      stage(Ab1, cur, 1, k2);
    }
    __builtin_amdgcn_s_barrier();
    __builtin_amdgcn_s_setprio(1);
#pragma unroll
    for (int mf = 0; mf < 4; mf++)
#pragma unroll
      for (int nf = 0; nf < 2; nf++)
#pragma unroll
        for (int kk = 0; kk < 2; kk++)
          acc[mf + 4][nf + 2] = MFMA16(af[mf][kk], b23[nf][kk], acc[mf + 4][nf + 2], 0, 0, 0);
    __builtin_amdgcn_s_setprio(0);
    if (t + 1 < NT) {
      if (t + 2 < NT)
        asm volatile("s_waitcnt vmcnt(4)" ::: "memory");
      else
        asm volatile("s_waitcnt vmcnt(0)" ::: "memory");
    }
    __builtin_amdgcn_s_barrier();
    cur ^= 1;
  }

#pragma unroll
  for (int mf = 0; mf < 8; mf++)
#pragma unroll
    for (int nf = 0; nf < 4; nf++) {
      size_t rbase = row0 + wave_m * 128 + mf * 16 + q4 * 4;
      size_t cc = col0 + wave_n * 64 + nf * 16 + r16;
#pragma unroll
      for (int jj = 0; jj < 4; jj++) {
        if constexpr (sizeof(OutT) == 2)
          Cc[(rbase + jj) * (size_t)N + cc] = f2bf(acc[mf][nf][jj]);
        else
          Cc[(rbase + jj) * (size_t)N + cc] = acc[mf][nf][jj];
      }
    }
}

// ---------------- flash attention: swapped-operand 32x32 MFMA, KVBLK=32 (r10/r14, best) ----
__global__ __launch_bounds__(256, 2) void attn(const unsigned short* __restrict__ Qn,
                                               const unsigned short* __restrict__ Kn,
                                               const unsigned short* __restrict__ Vt,
                                               unsigned short* __restrict__ Y) {
  __shared__ alignas(16) unsigned short lK[2][32 * 128];
  __shared__ alignas(16) unsigned short lV[2][128 * 32];

  int lin = blockIdx.x;
  int low3 = lin & 7, rest = lin >> 3;
  int chi = rest >> 6, idx = rest & 63;
  int c = (chi << 3) | low3;  // combo (b,kvh) 0..15, xcd-pinned via c&7
  int b = c >> 2, kvh = c & 3;
  int h = kvh * 4 + (idx >> 4);
  int qt = 15 - (idx & 15);  // heavy blocks first
  int Q0 = qt * 128;

  int lane = threadIdx.x & 63, w = threadIdx.x >> 6;  // 4 waves
  const int q5 = lane & 31, hi = lane >> 5, l7 = lane & 7;
  const int qrow = Q0 + w * 32 + q5;
  const unsigned short* Qp = Qn + ((size_t)(b * NH + h) * T_SEQ + qrow) * HD;
  const unsigned short* Kp = Kn + (size_t)(b * NKV + kvh) * T_SEQ * HD;
  const unsigned short* Vp = Vt + (size_t)(b * NKV + kvh) * HD * T_SEQ;

  short8 qf[8];
#pragma unroll
  for (int i = 0; i < 8; i++) qf[i] = *(const short8*)(Qp + i * 16 + hi * 8);

  f32x16 o4[4];
#pragma unroll
  for (int d = 0; d < 4; d++)
#pragma unroll
    for (int r = 0; r < 16; r++) o4[d][r] = 0.f;
  float mrow = -1e30f, Lp = 0.f;

  auto stageK = [&](int kv0, int buf) {
#pragma unroll
    for (int j = 0; j < 2; ++j) {
      int cw = w * 2 + j;
      int row = cw * 4 + (lane >> 4);
      int cb = lane & 15;
      gload_lds16(Kp + (size_t)(kv0 + row) * HD + ((cb ^ (row & 7)) * 8), &lK[buf][cw * 512]);
    }
  };
  auto stageV = [&](int kv0, int buf) {
#pragma unroll
    for (int j = 0; j < 2; ++j) {
      int cw = w * 2 + j;
      int row = cw * 16 + (lane >> 2);
      int ts = lane & 3;
      gload_lds16(Vp + (size_t)row * T_SEQ + kv0 + ((ts ^ (row & 3)) * 8), &lV[buf][cw * 512]);
    }
  };

  const int ntiles = 4 * qt + 4;
  const int ntw = (Q0 + w * 32 + 63) >> 5;

  stageK(0, 0);
  stageV(0, 0);
  __syncthreads();
  int cur = 0;

  for (int t = 0; t < ntiles; ++t) {
    int kv0 = t * 32;
    if (t + 1 < ntiles) { stageK(kv0 + 32, cur ^ 1); stageV(kv0 + 32, cur ^ 1); }
    if (t < ntw) {
      f32x16 st;
#pragma unroll
      for (int r = 0; r < 16; r++) st[r] = 0.f;
      __builtin_amdgcn_s_setprio(1);
#pragma unroll
      for (int i = 0; i < 8; i++) {
        short8 kf = *(const short8*)(&lK[cur][q5 * 128 + (((2 * i + hi) ^ l7) * 8)]);
        st = MFMA32(kf, qf[i], st, 0, 0, 0);
      }
      __builtin_amdgcn_s_setprio(0);
      if (kv0 + 31 > Q0 + w * 32) {
#pragma unroll
        for (int r = 0; r < 16; r++) {
          int kg = kv0 + (r & 3) + 8 * (r >> 2) + 4 * hi;
          if (kg > qrow) st[r] = -1e30f;
        }
      }
      float pm = st[0];
#pragma unroll
      for (int r = 1; r < 16; r++) pm = fmaxf(pm, st[r]);
      pm = fmaxf(pm, __shfl_xor(pm, 32));
      if (!__all(pm - mrow <= 8.0f)) {
        float mn = fmaxf(mrow, pm);
        float al = __expf(mrow - mn);
        mrow = mn;
        Lp *= al;
#pragma unroll
        for (int d = 0; d < 4; d++)
#pragma unroll
          for (int r = 0; r < 16; r++) o4[d][r] *= al;
      }
      float p[16];
#pragma unroll
      for (int r = 0; r < 16; r++) {
        p[r] = __expf(st[r] - mrow);
        Lp += p[r];
      }
#pragma unroll
      for (int ks = 0; ks < 2; ks++) {
        unsigned x0 = pkbf(p[8 * ks + 0], p[8 * ks + 1]);
        unsigned x1 = pkbf(p[8 * ks + 2], p[8 * ks + 3]);
        unsigned y0 = pkbf(p[8 * ks + 4], p[8 * ks + 5]);
        unsigned y1 = pkbf(p[8 * ks + 6], p[8 * ks + 7]);
        unsigned sx0 = __shfl_xor((int)x0, 32), sx1 = __shfl_xor((int)x1, 32);
        unsigned sy0 = __shfl_xor((int)y0, 32), sy1 = __shfl_xor((int)y1, 32);
        union { unsigned u[4]; short8 s; } pw;
        pw.u[0] = hi ? sy0 : x0;
        pw.u[1] = hi ? sy1 : x1;
        pw.u[2] = hi ? y0 : sx0;
        pw.u[3] = hi ? y1 : sx1;
        const int cb = 2 * ks + hi;
        __builtin_amdgcn_s_setprio(1);
#pragma unroll
        for (int db = 0; db < 4; db++) {
          int vrow = db * 32 + q5;
          short8 vf = *(const short8*)(&lV[cur][vrow * 32 + ((cb ^ (vrow & 3)) * 8)]);
          o4[db] = MFMA32(vf, pw.s, o4[db], 0, 0, 0);
        }
        __builtin_amdgcn_s_setprio(0);
      }
    }
    __syncthreads();
    cur ^= 1;
  }

  float L = Lp + __shfl_xor(Lp, 32);
  float linv = 1.f / L;
  unsigned short* Yp = Y + ((size_t)(b * T_SEQ) + qrow) * (NH * HD) + h * HD;
#pragma unroll
  for (int db = 0; db < 4; db++)
#pragma unroll
    for (int g = 0; g < 4; g++) {
      int d0 = db * 32 + g * 8 + 4 * hi;
      ushort4 v = make_ushort4(f2bf(o4[db][g * 4 + 0] * linv), f2bf(o4[db][g * 4 + 1] * linv),
                               f2bf(o4[db][g * 4 + 2] * linv), f2bf(o4[db][g * 4 + 3] * linv));
      *(ushort4*)(Yp + d0) = v;
    }
}

extern "C" void kernel_launch(void* const* d_in, const int* in_sizes, int n_in,
                              void* d_out, int out_size, void* d_ws, size_t ws_size,
                              hipStream_t stream) {
  const float* x = (const float*)d_in[0];
  const float* cosp = (const float*)d_in[1];
  const float* sinp = (const float*)d_in[2];
  const float* Wq = (const float*)d_in[3];
  const float* Wk = (const float*)d_in[4];
  const float* Wv = (const float*)d_in[5];
  const float* Wo = (const float*)d_in[6];
  float* out = (float*)d_out;

  char* ws = (char*)d_ws;
  size_t off = 0;
  auto alloc = [&](size_t bytes) { void* p = ws + off; off += bytes; return p; };
  const size_t BT = (size_t)B_SZ * T_SEQ;  // 8192
  unsigned short* xb = (unsigned short*)alloc(BT * C_DIM * 2);              // 32MB
  unsigned short* WqkvT = (unsigned short*)alloc((size_t)3072 * 2048 * 2);  // 12.6MB
  unsigned short* WoT = (unsigned short*)alloc((size_t)2048 * 2048 * 2);    // 8.4MB
  unsigned short* Qb = (unsigned short*)alloc(BT * 2048 * 2);               // 32MB
  unsigned short* Kb = (unsigned short*)alloc(BT * 512 * 2);                // 8MB
  unsigned short* Vb = (unsigned short*)alloc(BT * 512 * 2);                // 8MB
  unsigned short* Yb = (unsigned short*)alloc(BT * 2048 * 2);               // 32MB

  prep<<<26624, 256, 0, stream>>>(x, xb, Wq, Wk, Wv, Wo, WqkvT, WoT);

  // fused qkv GEMM + RoPE/RMSNorm/V-transpose: 768 blocks = 3.0 rounds
  gemm_qkv<<<768, 512, 0, stream>>>(xb, WqkvT, cosp, sinp, Qb, Kb, Vb, 2048, 64);

  attn<<<dim3(1024), 256, 0, stream>>>(Qb, Kb, Vb, Yb);

  gemm256<float><<<256, 512, 0, stream>>>(Yb, WoT, out, 2048, 2048, 32);
}

// Round 16
// 399.187 us; speedup vs baseline: 1.0254x; 1.0254x over previous
//
#include <hip/hip_runtime.h>
#include <hip/hip_bf16.h>

typedef __attribute__((ext_vector_type(8))) short short8;
typedef __attribute__((ext_vector_type(4))) float f32x4;
typedef __attribute__((ext_vector_type(16))) float f32x16;

#define B_SZ 4
#define T_SEQ 2048
#define C_DIM 2048
#define NH 16
#define NKV 4
#define HD 128

#define MFMA16 __builtin_amdgcn_mfma_f32_16x16x32_bf16
#define MFMA32 __builtin_amdgcn_mfma_f32_32x32x16_bf16

__device__ __forceinline__ unsigned short f2bf(float f) {
  union { __hip_bfloat16 h; unsigned short u; } v;
  v.h = __float2bfloat16(f);
  return v.u;
}
__device__ __forceinline__ float bf2f(unsigned short u) {
  union { unsigned short u; __hip_bfloat16 h; } v;
  v.u = u;
  return __bfloat162float(v.h);
}
__device__ __forceinline__ unsigned pkbf(float lo, float hi) {
  return (unsigned)f2bf(lo) | ((unsigned)f2bf(hi) << 16);
}

__device__ __forceinline__ void gload_lds16(const unsigned short* g, unsigned short* l) {
  __builtin_amdgcn_global_load_lds(
      (const __attribute__((address_space(1))) unsigned int*)g,
      (__attribute__((address_space(3))) unsigned int*)l, 16, 0, 0);
}

// ---------------- prep: cast x (bid < 16384) + all weight transposes (one launch) ----------
__global__ void prep(const float* __restrict__ x, unsigned short* __restrict__ xb,
                     const float* __restrict__ Wq, const float* __restrict__ Wk,
                     const float* __restrict__ Wv, const float* __restrict__ Wo,
                     unsigned short* __restrict__ WqkvT, unsigned short* __restrict__ WoT) {
  int bid = blockIdx.x, tid = threadIdx.x;
  if (bid < 16384) {
    int i = bid * 256 + tid;
    float4 f = ((const float4*)x)[i];
    ushort4 u = make_ushort4(f2bf(f.x), f2bf(f.y), f2bf(f.z), f2bf(f.w));
    ((ushort4*)xb)[i] = u;
    return;
  }
  __shared__ float tile[32][33];
  int idx = bid - 16384;        // 0..10239
  int y = idx >> 6, kx = idx & 63;
  const float* W;
  unsigned short* Wt;
  int N, n0;
  if (y < 64) { W = Wq; Wt = WqkvT; N = 2048; n0 = y * 32; }
  else if (y < 80) { W = Wk; Wt = WqkvT + (size_t)2048 * 2048; N = 512; n0 = (y - 64) * 32; }
  else if (y < 96) { W = Wv; Wt = WqkvT + (size_t)2560 * 2048; N = 512; n0 = (y - 80) * 32; }
  else { W = Wo; Wt = WoT; N = 2048; n0 = (y - 96) * 32; }
  int k0 = kx * 32;
  int tx = tid & 31, ty = tid >> 5;
#pragma unroll
  for (int i = 0; i < 4; i++)
    tile[ty + i * 8][tx] = W[(size_t)(k0 + ty + i * 8) * N + n0 + tx];
  __syncthreads();
#pragma unroll
  for (int i = 0; i < 4; i++)
    Wt[(size_t)(n0 + ty + i * 8) * 2048 + k0 + tx] = f2bf(tile[tx][ty + i * 8]);
}

// ---------------- 128x256 2-phase counted-vmcnt GEMM (qkv: 768 blocks = 3.0 rounds) ----
template <typename OutT>
__global__ __launch_bounds__(512, 2) void gemm128(const unsigned short* __restrict__ A,
                                                  const unsigned short* __restrict__ Bt,
                                                  OutT* __restrict__ Cc, int N, int K, int GX) {
  __shared__ alignas(16) unsigned short lds[2][3][128 * 64];  // 0=A, 1=B0, 2=B1
  const int tid = threadIdx.x, lane = tid & 63, wid = tid >> 6;
  const int wave_m = wid >> 2, wave_n = wid & 3;
  const int r16 = lane & 15, q4 = lane >> 4;
  const int sw = r16 & 7;

  int nwg = gridDim.x, orig = blockIdx.x;
  int qq = nwg >> 3, rr = nwg & 7;
  int xcd = orig & 7, loc = orig >> 3;
  int wg = (xcd < rr ? xcd * (qq + 1) : rr * (qq + 1) + (xcd - rr) * qq) + loc;
  int bx = wg % GX, by = wg / GX;
  const size_t row0 = (size_t)bx * 128, col0 = (size_t)by * 256;

  const unsigned short* Ab = A + row0 * K;
  const unsigned short* Bb0 = Bt + col0 * K;
  const unsigned short* Bb1 = Bt + (col0 + 128) * K;

  const int srow = lane >> 3, spb = lane & 7;
  auto stage = [&](const unsigned short* base, int buf, int slot, int k0) {
#pragma unroll
    for (int j = 0; j < 2; ++j) {
      int cw = j * 8 + wid;
      int row = cw * 8 + srow;
      gload_lds16(base + (size_t)row * K + k0 + ((spb ^ srow) * 8), &lds[buf][slot][cw * 512]);
    }
  };

  f32x4 acc[4][4];
  f32x4 zero = {0.f, 0.f, 0.f, 0.f};
#pragma unroll
  for (int m = 0; m < 4; m++)
#pragma unroll
    for (int n = 0; n < 4; n++) acc[m][n] = zero;

  const int NT = K / 64;
  stage(Ab, 0, 0, 0);
  stage(Bb0, 0, 1, 0);
  stage(Bb1, 0, 2, 0);
  stage(Ab, 1, 0, 64);
  asm volatile("s_waitcnt vmcnt(2)" ::: "memory");
  __builtin_amdgcn_s_barrier();

  short8 af[4][2], b01[2][2], b23[2][2];
  const int bslot = 1 + (wave_n >> 1);
  const int bro = (wave_n & 1) * 64;

  int cur = 0;
#pragma unroll 1
  for (int t = 0; t < NT; ++t) {
    const unsigned short* Ah = &lds[cur][0][0];
    const unsigned short* Bh = &lds[cur][bslot][0];
    const int k1 = t * 64 + 64, k2 = t * 64 + 128;
#pragma unroll
    for (int mf = 0; mf < 4; mf++)
#pragma unroll
      for (int kk = 0; kk < 2; kk++)
        af[mf][kk] =
            *(const short8*)(Ah + (wave_m * 64 + mf * 16 + r16) * 64 + (((kk * 4 + q4) ^ sw) * 8));
#pragma unroll
    for (int nf = 0; nf < 2; nf++)
#pragma unroll
      for (int kk = 0; kk < 2; kk++)
        b01[nf][kk] =
            *(const short8*)(Bh + (bro + nf * 16 + r16) * 64 + (((kk * 4 + q4) ^ sw) * 8));
    if (t + 1 < NT) stage(Bb0, cur ^ 1, 1, k1);
    __builtin_amdgcn_s_barrier();
    asm volatile("s_waitcnt lgkmcnt(0)" ::: "memory");
    __builtin_amdgcn_s_setprio(1);
#pragma unroll
    for (int mf = 0; mf < 4; mf++)
#pragma unroll
      for (int nf = 0; nf < 2; nf++)
#pragma unroll
        for (int kk = 0; kk < 2; kk++)
          acc[mf][nf] = MFMA16(af[mf][kk], b01[nf][kk], acc[mf][nf], 0, 0, 0);
    __builtin_amdgcn_s_setprio(0);
    __builtin_amdgcn_s_barrier();
#pragma unroll
    for (int nf = 0; nf < 2; nf++)
#pragma unroll
      for (int kk = 0; kk < 2; kk++)
        b23[nf][kk] =
            *(const short8*)(Bh + (bro + (nf + 2) * 16 + r16) * 64 + (((kk * 4 + q4) ^ sw) * 8));
    if (t + 1 < NT) stage(Bb1, cur ^ 1, 2, k1);
    if (t + 2 < NT) stage(Ab, cur, 0, k2);
    __builtin_amdgcn_s_barrier();
    asm volatile("s_waitcnt lgkmcnt(0)" ::: "memory");
    __builtin_amdgcn_s_setprio(1);
#pragma unroll
    for (int mf = 0; mf < 4; mf++)
#pragma unroll
      for (int nf = 0; nf < 2; nf++)
#pragma unroll
        for (int kk = 0; kk < 2; kk++)
          acc[mf][nf + 2] = MFMA16(af[mf][kk], b23[nf][kk], acc[mf][nf + 2], 0, 0, 0);
    __builtin_amdgcn_s_setprio(0);
    if (t + 2 < NT)
      asm volatile("s_waitcnt vmcnt(2)" ::: "memory");
    else if (t + 1 < NT)
      asm volatile("s_waitcnt vmcnt(0)" ::: "memory");
    __builtin_amdgcn_s_barrier();
    cur ^= 1;
  }

#pragma unroll
  for (int mf = 0; mf < 4; mf++)
#pragma unroll
    for (int nf = 0; nf < 4; nf++) {
      size_t rbase = row0 + wave_m * 64 + mf * 16 + q4 * 4;
      size_t cc = col0 + wave_n * 64 + nf * 16 + r16;
#pragma unroll
      for (int jj = 0; jj < 4; jj++) {
        if constexpr (sizeof(OutT) == 2)
          Cc[(rbase + jj) * (size_t)N + cc] = f2bf(acc[mf][nf][jj]);
        else
          Cc[(rbase + jj) * (size_t)N + cc] = acc[mf][nf][jj];
      }
    }
}

// ---------------- 256x256 8-phase GEMM (out-proj: 256 blocks = 1.0 round) ----------------
template <typename OutT>
__global__ __launch_bounds__(512, 2) void gemm256(const unsigned short* __restrict__ A,
                                                  const unsigned short* __restrict__ Bt,
                                                  OutT* __restrict__ Cc, int N, int K, int GX) {
  __shared__ alignas(16) unsigned short lds[2][4][128 * 64];
  const int tid = threadIdx.x, lane = tid & 63, wid = tid >> 6;
  const int wave_m = wid >> 2, wave_n = wid & 3;
  const int r16 = lane & 15, q4 = lane >> 4;
  const int sw = r16 & 7;

  int nwg = gridDim.x, orig = blockIdx.x;
  int qq = nwg >> 3, rr = nwg & 7;
  int xcd = orig & 7, loc = orig >> 3;
  int wg = (xcd < rr ? xcd * (qq + 1) : rr * (qq + 1) + (xcd - rr) * qq) + loc;
  int bx = wg % GX, by = wg / GX;
  const size_t row0 = (size_t)bx * 256, col0 = (size_t)by * 256;

  const unsigned short* Ab0 = A + row0 * K;
  const unsigned short* Ab1 = A + (row0 + 128) * K;
  const unsigned short* Bb0 = Bt + col0 * K;
  const unsigned short* Bb1 = Bt + (col0 + 128) * K;

  const int srow = lane >> 3, spb = lane & 7;
  auto stage = [&](const unsigned short* base, int buf, int slot, int k0) {
#pragma unroll
    for (int j = 0; j < 2; ++j) {
      int cw = j * 8 + wid;
      int row = cw * 8 + srow;
      gload_lds16(base + (size_t)row * K + k0 + ((spb ^ srow) * 8), &lds[buf][slot][cw * 512]);
    }
  };

  f32x4 acc[8][4];
  f32x4 zero = {0.f, 0.f, 0.f, 0.f};
#pragma unroll
  for (int m = 0; m < 8; m++)
#pragma unroll
    for (int n = 0; n < 4; n++) acc[m][n] = zero;

  const int NT = K / 64;
  stage(Ab0, 0, 0, 0);
  stage(Ab1, 0, 1, 0);
  stage(Bb0, 0, 2, 0);
  stage(Bb1, 0, 3, 0);
  stage(Ab0, 1, 0, 64);
  stage(Ab1, 1, 1, 64);
  asm volatile("s_waitcnt vmcnt(4)" ::: "memory");
  __builtin_amdgcn_s_barrier();

  short8 af[4][2], b01[2][2], b23[2][2];
  const int bslot = 2 + (wave_n >> 1);
  const int bro = (wave_n & 1) * 64;

  int cur = 0;
#pragma unroll 1
  for (int t = 0; t < NT; ++t) {
    const unsigned short* Ah = &lds[cur][wave_m][0];
    const unsigned short* Bh = &lds[cur][bslot][0];
    const int k1 = t * 64 + 64, k2 = t * 64 + 128;
#pragma unroll
    for (int mf = 0; mf < 4; mf++)
#pragma unroll
      for (int kk = 0; kk < 2; kk++)
        af[mf][kk] = *(const short8*)(Ah + (mf * 16 + r16) * 64 + (((kk * 4 + q4) ^ sw) * 8));
#pragma unroll
    for (int nf = 0; nf < 2; nf++)
#pragma unroll
      for (int kk = 0; kk < 2; kk++)
        b01[nf][kk] =
            *(const short8*)(Bh + (bro + nf * 16 + r16) * 64 + (((kk * 4 + q4) ^ sw) * 8));
    if (t + 1 < NT) stage(Bb0, cur ^ 1, 2, k1);
    __builtin_amdgcn_s_barrier();
    asm volatile("s_waitcnt lgkmcnt(0)" ::: "memory");
    __builtin_amdgcn_s_setprio(1);
#pragma unroll
    for (int mf = 0; mf < 4; mf++)
#pragma unroll
      for (int nf = 0; nf < 2; nf++)
#pragma unroll
        for (int kk = 0; kk < 2; kk++)
          acc[mf][nf] = MFMA16(af[mf][kk], b01[nf][kk], acc[mf][nf], 0, 0, 0);
    __builtin_amdgcn_s_setprio(0);
    __builtin_amdgcn_s_barrier();
#pragma unroll
    for (int nf = 0; nf < 2; nf++)
#pragma unroll
      for (int kk = 0; kk < 2; kk++)
        b23[nf][kk] =
            *(const short8*)(Bh + (bro + (nf + 2) * 16 + r16) * 64 + (((kk * 4 + q4) ^ sw) * 8));
    if (t + 1 < NT) stage(Bb1, cur ^ 1, 3, k1);
    __builtin_amdgcn_s_barrier();
    asm volatile("s_waitcnt lgkmcnt(0)" ::: "memory");
    __builtin_amdgcn_s_setprio(1);
#pragma unroll
    for (int mf = 0; mf < 4; mf++)
#pragma unroll
      for (int nf = 0; nf < 2; nf++)
#pragma unroll
        for (int kk = 0; kk < 2; kk++)
          acc[mf][nf + 2] = MFMA16(af[mf][kk], b23[nf][kk], acc[mf][nf + 2], 0, 0, 0);
    __builtin_amdgcn_s_setprio(0);
    __builtin_amdgcn_s_barrier();
#pragma unroll
    for (int mf = 0; mf < 4; mf++)
#pragma unroll
      for (int kk = 0; kk < 2; kk++)
        af[mf][kk] =
            *(const short8*)(Ah + ((mf + 4) * 16 + r16) * 64 + (((kk * 4 + q4) ^ sw) * 8));
    __builtin_amdgcn_s_barrier();
    asm volatile("s_waitcnt lgkmcnt(0)" ::: "memory");
    __builtin_amdgcn_s_setprio(1);
#pragma unroll
    for (int mf = 0; mf < 4; mf++)
#pragma unroll
      for (int nf = 0; nf < 2; nf++)
#pragma unroll
        for (int kk = 0; kk < 2; kk++)
          acc[mf + 4][nf] = MFMA16(af[mf][kk], b01[nf][kk], acc[mf + 4][nf], 0, 0, 0);
    __builtin_amdgcn_s_setprio(0);
    __builtin_amdgcn_s_barrier();
    if (t + 2 < NT) {
      stage(Ab0, cur, 0, k2);
      stage(Ab1, cur, 1, k2);
    }
    __builtin_amdgcn_s_barrier();
    __builtin_amdgcn_s_setprio(1);
#pragma unroll
    for (int mf = 0; mf < 4; mf++)
#pragma unroll
      for (int nf = 0; nf < 2; nf++)
#pragma unroll
        for (int kk = 0; kk < 2; kk++)
          acc[mf + 4][nf + 2] = MFMA16(af[mf][kk], b23[nf][kk], acc[mf + 4][nf + 2], 0, 0, 0);
    __builtin_amdgcn_s_setprio(0);
    if (t + 1 < NT) {
      if (t + 2 < NT)
        asm volatile("s_waitcnt vmcnt(4)" ::: "memory");
      else
        asm volatile("s_waitcnt vmcnt(0)" ::: "memory");
    }
    __builtin_amdgcn_s_barrier();
    cur ^= 1;
  }

#pragma unroll
  for (int mf = 0; mf < 8; mf++)
#pragma unroll
    for (int nf = 0; nf < 4; nf++) {
      size_t rbase = row0 + wave_m * 128 + mf * 16 + q4 * 4;
      size_t cc = col0 + wave_n * 64 + nf * 16 + r16;
#pragma unroll
      for (int jj = 0; jj < 4; jj++) {
        if constexpr (sizeof(OutT) == 2)
          Cc[(rbase + jj) * (size_t)N + cc] = f2bf(acc[mf][nf][jj]);
        else
          Cc[(rbase + jj) * (size_t)N + cc] = acc[mf][nf][jj];
      }
    }
}

// ---------------- merged RoPE+RMSNorm (bid<40960) + V transpose (rest), one launch --------
__global__ void ropevt(const unsigned short* __restrict__ qkv, const float* __restrict__ cosp,
                       const float* __restrict__ sinp, unsigned short* __restrict__ Qb,
                       unsigned short* __restrict__ Kb, unsigned short* __restrict__ Vt) {
  int bid = blockIdx.x, tid = threadIdx.x;
  if (bid < 40960) {
    int gid = bid * 4 + (tid >> 6);
    int lane = tid & 63;
    int hh = gid % 20;
    int bt = gid / 20;
    int t = bt % T_SEQ, b = bt / T_SEQ;
    int colbase;
    unsigned short* dst;
    float outscale;
    if (hh < 16) {
      colbase = hh * HD;
      dst = Qb + ((size_t)(b * NH + hh) * T_SEQ + t) * HD;
      outscale = 0.08838834764831845f;  // 1/sqrt(128)
    } else {
      int h2 = hh - 16;
      colbase = 2048 + h2 * HD;
      dst = Kb + ((size_t)(b * NKV + h2) * T_SEQ + t) * HD;
      outscale = 1.0f;
    }
    const unsigned short* src = qkv + (size_t)(b * T_SEQ + t) * 3072 + colbase;
    float x1 = bf2f(src[lane]), x2 = bf2f(src[64 + lane]);
    float c = cosp[t * 64 + lane], s = sinp[t * 64 + lane];
    float y1 = x1 * c + x2 * s;
    float y2 = x2 * c - x1 * s;
    float ss = y1 * y1 + y2 * y2;
#pragma unroll
    for (int d = 1; d < 64; d <<= 1) ss += __shfl_xor(ss, d);
    float r = rsqrtf(ss * (1.f / 128.f) + 1e-6f) * outscale;
    dst[lane] = f2bf(y1 * r);
    dst[64 + lane] = f2bf(y2 * r);
    return;
  }
  // ---- V transpose: qkv cols [2560+kvh*128+d] -> Vt (B,KVH,D,T) ----
  __shared__ unsigned short tile[32][34];
  int idx = bid - 40960;  // 0..4095
  int xg = idx & 63, rem = idx >> 6;
  int yg = rem & 3, zg = rem >> 2;
  int t0 = xg * 32, d0 = yg * 32;
  int b = zg >> 2, kvh = zg & 3;
  int tx = tid & 31, ty = tid >> 5;
#pragma unroll
  for (int i = 0; i < 4; i++)
    tile[ty + i * 8][tx] =
        qkv[(size_t)(b * T_SEQ + t0 + ty + i * 8) * 3072 + 2560 + kvh * HD + d0 + tx];
  __syncthreads();
#pragma unroll
  for (int i = 0; i < 4; i++)
    Vt[((size_t)(b * NKV + kvh) * HD + d0 + ty + i * 8) * T_SEQ + t0 + tx] = tile[tx][ty + i * 8];
}

// ---------------- flash attention: swapped-operand 32x32 MFMA, KVBLK=32 (r10/r14, best) ----
__global__ __launch_bounds__(256, 2) void attn(const unsigned short* __restrict__ Qn,
                                               const unsigned short* __restrict__ Kn,
                                               const unsigned short* __restrict__ Vt,
                                               unsigned short* __restrict__ Y) {
  __shared__ alignas(16) unsigned short lK[2][32 * 128];
  __shared__ alignas(16) unsigned short lV[2][128 * 32];

  int lin = blockIdx.x;
  int low3 = lin & 7, rest = lin >> 3;
  int chi = rest >> 6, idx = rest & 63;
  int c = (chi << 3) | low3;  // combo (b,kvh) 0..15, xcd-pinned via c&7
  int b = c >> 2, kvh = c & 3;
  int h = kvh * 4 + (idx >> 4);
  int qt = 15 - (idx & 15);  // heavy blocks first
  int Q0 = qt * 128;

  int lane = threadIdx.x & 63, w = threadIdx.x >> 6;  // 4 waves
  const int q5 = lane & 31, hi = lane >> 5, l7 = lane & 7;
  const int qrow = Q0 + w * 32 + q5;
  const unsigned short* Qp = Qn + ((size_t)(b * NH + h) * T_SEQ + qrow) * HD;
  const unsigned short* Kp = Kn + (size_t)(b * NKV + kvh) * T_SEQ * HD;
  const unsigned short* Vp = Vt + (size_t)(b * NKV + kvh) * HD * T_SEQ;

  short8 qf[8];
#pragma unroll
  for (int i = 0; i < 8; i++) qf[i] = *(const short8*)(Qp + i * 16 + hi * 8);

  f32x16 o4[4];
#pragma unroll
  for (int d = 0; d < 4; d++)
#pragma unroll
    for (int r = 0; r < 16; r++) o4[d][r] = 0.f;
  float mrow = -1e30f, Lp = 0.f;

  auto stageK = [&](int kv0, int buf) {
#pragma unroll
    for (int j = 0; j < 2; ++j) {
      int cw = w * 2 + j;
      int row = cw * 4 + (lane >> 4);
      int cb = lane & 15;
      gload_lds16(Kp + (size_t)(kv0 + row) * HD + ((cb ^ (row & 7)) * 8), &lK[buf][cw * 512]);
    }
  };
  auto stageV = [&](int kv0, int buf) {
#pragma unroll
    for (int j = 0; j < 2; ++j) {
      int cw = w * 2 + j;
      int row = cw * 16 + (lane >> 2);
      int ts = lane & 3;
      gload_lds16(Vp + (size_t)row * T_SEQ + kv0 + ((ts ^ (row & 3)) * 8), &lV[buf][cw * 512]);
    }
  };

  const int ntiles = 4 * qt + 4;
  const int ntw = (Q0 + w * 32 + 63) >> 5;

  stageK(0, 0);
  stageV(0, 0);
  __syncthreads();
  int cur = 0;

  for (int t = 0; t < ntiles; ++t) {
    int kv0 = t * 32;
    if (t + 1 < ntiles) { stageK(kv0 + 32, cur ^ 1); stageV(kv0 + 32, cur ^ 1); }
    if (t < ntw) {
      f32x16 st;
#pragma unroll
      for (int r = 0; r < 16; r++) st[r] = 0.f;
      __builtin_amdgcn_s_setprio(1);
#pragma unroll
      for (int i = 0; i < 8; i++) {
        short8 kf = *(const short8*)(&lK[cur][q5 * 128 + (((2 * i + hi) ^ l7) * 8)]);
        st = MFMA32(kf, qf[i], st, 0, 0, 0);
      }
      __builtin_amdgcn_s_setprio(0);
      if (kv0 + 31 > Q0 + w * 32) {
#pragma unroll
        for (int r = 0; r < 16; r++) {
          int kg = kv0 + (r & 3) + 8 * (r >> 2) + 4 * hi;
          if (kg > qrow) st[r] = -1e30f;
        }
      }
      float pm = st[0];
#pragma unroll
      for (int r = 1; r < 16; r++) pm = fmaxf(pm, st[r]);
      pm = fmaxf(pm, __shfl_xor(pm, 32));
      if (!__all(pm - mrow <= 8.0f)) {
        float mn = fmaxf(mrow, pm);
        float al = __expf(mrow - mn);
        mrow = mn;
        Lp *= al;
#pragma unroll
        for (int d = 0; d < 4; d++)
#pragma unroll
          for (int r = 0; r < 16; r++) o4[d][r] *= al;
      }
      float p[16];
#pragma unroll
      for (int r = 0; r < 16; r++) {
        p[r] = __expf(st[r] - mrow);
        Lp += p[r];
      }
#pragma unroll
      for (int ks = 0; ks < 2; ks++) {
        unsigned x0 = pkbf(p[8 * ks + 0], p[8 * ks + 1]);
        unsigned x1 = pkbf(p[8 * ks + 2], p[8 * ks + 3]);
        unsigned y0 = pkbf(p[8 * ks + 4], p[8 * ks + 5]);
        unsigned y1 = pkbf(p[8 * ks + 6], p[8 * ks + 7]);
        unsigned sx0 = __shfl_xor((int)x0, 32), sx1 = __shfl_xor((int)x1, 32);
        unsigned sy0 = __shfl_xor((int)y0, 32), sy1 = __shfl_xor((int)y1, 32);
        union { unsigned u[4]; short8 s; } pw;
        pw.u[0] = hi ? sy0 : x0;
        pw.u[1] = hi ? sy1 : x1;
        pw.u[2] = hi ? y0 : sx0;
        pw.u[3] = hi ? y1 : sx1;
        const int cb = 2 * ks + hi;
        __builtin_amdgcn_s_setprio(1);
#pragma unroll
        for (int db = 0; db < 4; db++) {
          int vrow = db * 32 + q5;
          short8 vf = *(const short8*)(&lV[cur][vrow * 32 + ((cb ^ (vrow & 3)) * 8)]);
          o4[db] = MFMA32(vf, pw.s, o4[db], 0, 0, 0);
        }
        __builtin_amdgcn_s_setprio(0);
      }
    }
    __syncthreads();
    cur ^= 1;
  }

  float L = Lp + __shfl_xor(Lp, 32);
  float linv = 1.f / L;
  unsigned short* Yp = Y + ((size_t)(b * T_SEQ) + qrow) * (NH * HD) + h * HD;
#pragma unroll
  for (int db = 0; db < 4; db++)
#pragma unroll
    for (int g = 0; g < 4; g++) {
      int d0 = db * 32 + g * 8 + 4 * hi;
      ushort4 v = make_ushort4(f2bf(o4[db][g * 4 + 0] * linv), f2bf(o4[db][g * 4 + 1] * linv),
                               f2bf(o4[db][g * 4 + 2] * linv), f2bf(o4[db][g * 4 + 3] * linv));
      *(ushort4*)(Yp + d0) = v;
    }
}

extern "C" void kernel_launch(void* const* d_in, const int* in_sizes, int n_in,
                              void* d_out, int out_size, void* d_ws, size_t ws_size,
                              hipStream_t stream) {
  const float* x = (const float*)d_in[0];
  const float* cosp = (const float*)d_in[1];
  const float* sinp = (const float*)d_in[2];
  const float* Wq = (const float*)d_in[3];
  const float* Wk = (const float*)d_in[4];
  const float* Wv = (const float*)d_in[5];
  const float* Wo = (const float*)d_in[6];
  float* out = (float*)d_out;

  char* ws = (char*)d_ws;
  size_t off = 0;
  auto alloc = [&](size_t bytes) { void* p = ws + off; off += bytes; return p; };
  const size_t BT = (size_t)B_SZ * T_SEQ;  // 8192
  unsigned short* xb = (unsigned short*)alloc(BT * C_DIM * 2);              // 32MB
  unsigned short* WqkvT = (unsigned short*)alloc((size_t)3072 * 2048 * 2);  // 12.6MB
  unsigned short* WoT = (unsigned short*)alloc((size_t)2048 * 2048 * 2);    // 8.4MB
  unsigned short* qkv = (unsigned short*)alloc(BT * 3072 * 2);              // 48MB
  unsigned short* Kb = (unsigned short*)alloc(BT * 512 * 2);                // 8MB
  unsigned short* Vb = (unsigned short*)alloc(BT * 512 * 2);                // 8MB
  unsigned short* Qb = xb;   // alias: xb dead after qkv GEMM
  unsigned short* Yb = qkv;  // alias: qkv dead after ropevt

  prep<<<26624, 256, 0, stream>>>(x, xb, Wq, Wk, Wv, Wo, WqkvT, WoT);

  gemm128<unsigned short><<<768, 512, 0, stream>>>(xb, WqkvT, qkv, 3072, 2048, 64);

  ropevt<<<45056, 256, 0, stream>>>(qkv, cosp, sinp, Qb, Kb, Vb);

  attn<<<dim3(1024), 256, 0, stream>>>(Qb, Kb, Vb, Yb);

  gemm256<float><<<256, 512, 0, stream>>>(Yb, WoT, out, 2048, 2048, 32);
}

// Round 17
// 378.859 us; speedup vs baseline: 1.0804x; 1.0537x over previous
//
#include <hip/hip_runtime.h>
#include <hip/hip_bf16.h>

typedef __attribute__((ext_vector_type(8))) short short8;
typedef __attribute__((ext_vector_type(4))) float f32x4;
typedef __attribute__((ext_vector_type(16))) float f32x16;

#define B_SZ 4
#define T_SEQ 2048
#define C_DIM 2048
#define NH 16
#define NKV 4
#define HD 128

#define MFMA16 __builtin_amdgcn_mfma_f32_16x16x32_bf16
#define MFMA32 __builtin_amdgcn_mfma_f32_32x32x16_bf16

__device__ __forceinline__ unsigned short f2bf(float f) {
  union { __hip_bfloat16 h; unsigned short u; } v;
  v.h = __float2bfloat16(f);
  return v.u;
}
__device__ __forceinline__ float bf2f(unsigned short u) {
  union { unsigned short u; __hip_bfloat16 h; } v;
  v.u = u;
  return __bfloat162float(v.h);
}
__device__ __forceinline__ unsigned pkbf(float lo, float hi) {
  return (unsigned)f2bf(lo) | ((unsigned)f2bf(hi) << 16);
}

__device__ __forceinline__ void gload_lds16(const unsigned short* g, unsigned short* l) {
  __builtin_amdgcn_global_load_lds(
      (const __attribute__((address_space(1))) unsigned int*)g,
      (__attribute__((address_space(3))) unsigned int*)l, 16, 0, 0);
}

// ---------------- prep: cast x (bid < 16384) + all weight transposes (one launch) ----------
__global__ void prep(const float* __restrict__ x, unsigned short* __restrict__ xb,
                     const float* __restrict__ Wq, const float* __restrict__ Wk,
                     const float* __restrict__ Wv, const float* __restrict__ Wo,
                     unsigned short* __restrict__ WqkvT, unsigned short* __restrict__ WoT) {
  int bid = blockIdx.x, tid = threadIdx.x;
  if (bid < 16384) {
    int i = bid * 256 + tid;
    float4 f = ((const float4*)x)[i];
    ushort4 u = make_ushort4(f2bf(f.x), f2bf(f.y), f2bf(f.z), f2bf(f.w));
    ((ushort4*)xb)[i] = u;
    return;
  }
  __shared__ float tile[32][33];
  int idx = bid - 16384;        // 0..10239
  int y = idx >> 6, kx = idx & 63;
  const float* W;
  unsigned short* Wt;
  int N, n0;
  if (y < 64) { W = Wq; Wt = WqkvT; N = 2048; n0 = y * 32; }
  else if (y < 80) { W = Wk; Wt = WqkvT + (size_t)2048 * 2048; N = 512; n0 = (y - 64) * 32; }
  else if (y < 96) { W = Wv; Wt = WqkvT + (size_t)2560 * 2048; N = 512; n0 = (y - 80) * 32; }
  else { W = Wo; Wt = WoT; N = 2048; n0 = (y - 96) * 32; }
  int k0 = kx * 32;
  int tx = tid & 31, ty = tid >> 5;
#pragma unroll
  for (int i = 0; i < 4; i++)
    tile[ty + i * 8][tx] = W[(size_t)(k0 + ty + i * 8) * N + n0 + tx];
  __syncthreads();
#pragma unroll
  for (int i = 0; i < 4; i++)
    Wt[(size_t)(n0 + ty + i * 8) * 2048 + k0 + tx] = f2bf(tile[tx][ty + i * 8]);
}

// ---------------- 128x256 2-phase counted-vmcnt GEMM (qkv: 768 blocks = 3.0 rounds) ----
template <typename OutT>
__global__ __launch_bounds__(512, 2) void gemm128(const unsigned short* __restrict__ A,
                                                  const unsigned short* __restrict__ Bt,
                                                  OutT* __restrict__ Cc, int N, int K, int GX) {
  __shared__ alignas(16) unsigned short lds[2][3][128 * 64];  // 0=A, 1=B0, 2=B1
  const int tid = threadIdx.x, lane = tid & 63, wid = tid >> 6;
  const int wave_m = wid >> 2, wave_n = wid & 3;
  const int r16 = lane & 15, q4 = lane >> 4;
  const int sw = r16 & 7;

  int nwg = gridDim.x, orig = blockIdx.x;
  int qq = nwg >> 3, rr = nwg & 7;
  int xcd = orig & 7, loc = orig >> 3;
  int wg = (xcd < rr ? xcd * (qq + 1) : rr * (qq + 1) + (xcd - rr) * qq) + loc;
  int bx = wg % GX, by = wg / GX;
  const size_t row0 = (size_t)bx * 128, col0 = (size_t)by * 256;

  const unsigned short* Ab = A + row0 * K;
  const unsigned short* Bb0 = Bt + col0 * K;
  const unsigned short* Bb1 = Bt + (col0 + 128) * K;

  const int srow = lane >> 3, spb = lane & 7;
  auto stage = [&](const unsigned short* base, int buf, int slot, int k0) {
#pragma unroll
    for (int j = 0; j < 2; ++j) {
      int cw = j * 8 + wid;
      int row = cw * 8 + srow;
      gload_lds16(base + (size_t)row * K + k0 + ((spb ^ srow) * 8), &lds[buf][slot][cw * 512]);
    }
  };

  f32x4 acc[4][4];
  f32x4 zero = {0.f, 0.f, 0.f, 0.f};
#pragma unroll
  for (int m = 0; m < 4; m++)
#pragma unroll
    for (int n = 0; n < 4; n++) acc[m][n] = zero;

  const int NT = K / 64;
  stage(Ab, 0, 0, 0);
  stage(Bb0, 0, 1, 0);
  stage(Bb1, 0, 2, 0);
  stage(Ab, 1, 0, 64);
  asm volatile("s_waitcnt vmcnt(2)" ::: "memory");
  __builtin_amdgcn_s_barrier();

  short8 af[4][2], b01[2][2], b23[2][2];
  const int bslot = 1 + (wave_n >> 1);
  const int bro = (wave_n & 1) * 64;

  int cur = 0;
#pragma unroll 1
  for (int t = 0; t < NT; ++t) {
    const unsigned short* Ah = &lds[cur][0][0];
    const unsigned short* Bh = &lds[cur][bslot][0];
    const int k1 = t * 64 + 64, k2 = t * 64 + 128;
#pragma unroll
    for (int mf = 0; mf < 4; mf++)
#pragma unroll
      for (int kk = 0; kk < 2; kk++)
        af[mf][kk] =
            *(const short8*)(Ah + (wave_m * 64 + mf * 16 + r16) * 64 + (((kk * 4 + q4) ^ sw) * 8));
#pragma unroll
    for (int nf = 0; nf < 2; nf++)
#pragma unroll
      for (int kk = 0; kk < 2; kk++)
        b01[nf][kk] =
            *(const short8*)(Bh + (bro + nf * 16 + r16) * 64 + (((kk * 4 + q4) ^ sw) * 8));
    if (t + 1 < NT) stage(Bb0, cur ^ 1, 1, k1);
    __builtin_amdgcn_s_barrier();
    asm volatile("s_waitcnt lgkmcnt(0)" ::: "memory");
    __builtin_amdgcn_s_setprio(1);
#pragma unroll
    for (int mf = 0; mf < 4; mf++)
#pragma unroll
      for (int nf = 0; nf < 2; nf++)
#pragma unroll
        for (int kk = 0; kk < 2; kk++)
          acc[mf][nf] = MFMA16(af[mf][kk], b01[nf][kk], acc[mf][nf], 0, 0, 0);
    __builtin_amdgcn_s_setprio(0);
    __builtin_amdgcn_s_barrier();
#pragma unroll
    for (int nf = 0; nf < 2; nf++)
#pragma unroll
      for (int kk = 0; kk < 2; kk++)
        b23[nf][kk] =
            *(const short8*)(Bh + (bro + (nf + 2) * 16 + r16) * 64 + (((kk * 4 + q4) ^ sw) * 8));
    if (t + 1 < NT) stage(Bb1, cur ^ 1, 2, k1);
    if (t + 2 < NT) stage(Ab, cur, 0, k2);
    __builtin_amdgcn_s_barrier();
    asm volatile("s_waitcnt lgkmcnt(0)" ::: "memory");
    __builtin_amdgcn_s_setprio(1);
#pragma unroll
    for (int mf = 0; mf < 4; mf++)
#pragma unroll
      for (int nf = 0; nf < 2; nf++)
#pragma unroll
        for (int kk = 0; kk < 2; kk++)
          acc[mf][nf + 2] = MFMA16(af[mf][kk], b23[nf][kk], acc[mf][nf + 2], 0, 0, 0);
    __builtin_amdgcn_s_setprio(0);
    if (t + 2 < NT)
      asm volatile("s_waitcnt vmcnt(2)" ::: "memory");
    else if (t + 1 < NT)
      asm volatile("s_waitcnt vmcnt(0)" ::: "memory");
    __builtin_amdgcn_s_barrier();
    cur ^= 1;
  }

#pragma unroll
  for (int mf = 0; mf < 4; mf++)
#pragma unroll
    for (int nf = 0; nf < 4; nf++) {
      size_t rbase = row0 + wave_m * 64 + mf * 16 + q4 * 4;
      size_t cc = col0 + wave_n * 64 + nf * 16 + r16;
#pragma unroll
      for (int jj = 0; jj < 4; jj++) {
        if constexpr (sizeof(OutT) == 2)
          Cc[(rbase + jj) * (size_t)N + cc] = f2bf(acc[mf][nf][jj]);
        else
          Cc[(rbase + jj) * (size_t)N + cc] = acc[mf][nf][jj];
      }
    }
}

// ---------------- 256x256 8-phase GEMM (out-proj: 256 blocks = 1.0 round) ----------------
template <typename OutT>
__global__ __launch_bounds__(512, 2) void gemm256(const unsigned short* __restrict__ A,
                                                  const unsigned short* __restrict__ Bt,
                                                  OutT* __restrict__ Cc, int N, int K, int GX) {
  __shared__ alignas(16) unsigned short lds[2][4][128 * 64];
  const int tid = threadIdx.x, lane = tid & 63, wid = tid >> 6;
  const int wave_m = wid >> 2, wave_n = wid & 3;
  const int r16 = lane & 15, q4 = lane >> 4;
  const int sw = r16 & 7;

  int nwg = gridDim.x, orig = blockIdx.x;
  int qq = nwg >> 3, rr = nwg & 7;
  int xcd = orig & 7, loc = orig >> 3;
  int wg = (xcd < rr ? xcd * (qq + 1) : rr * (qq + 1) + (xcd - rr) * qq) + loc;
  int bx = wg % GX, by = wg / GX;
  const size_t row0 = (size_t)bx * 256, col0 = (size_t)by * 256;

  const unsigned short* Ab0 = A + row0 * K;
  const unsigned short* Ab1 = A + (row0 + 128) * K;
  const unsigned short* Bb0 = Bt + col0 * K;
  const unsigned short* Bb1 = Bt + (col0 + 128) * K;

  const int srow = lane >> 3, spb = lane & 7;
  auto stage = [&](const unsigned short* base, int buf, int slot, int k0) {
#pragma unroll
    for (int j = 0; j < 2; ++j) {
      int cw = j * 8 + wid;
      int row = cw * 8 + srow;
      gload_lds16(base + (size_t)row * K + k0 + ((spb ^ srow) * 8), &lds[buf][slot][cw * 512]);
    }
  };

  f32x4 acc[8][4];
  f32x4 zero = {0.f, 0.f, 0.f, 0.f};
#pragma unroll
  for (int m = 0; m < 8; m++)
#pragma unroll
    for (int n = 0; n < 4; n++) acc[m][n] = zero;

  const int NT = K / 64;
  stage(Ab0, 0, 0, 0);
  stage(Ab1, 0, 1, 0);
  stage(Bb0, 0, 2, 0);
  stage(Bb1, 0, 3, 0);
  stage(Ab0, 1, 0, 64);
  stage(Ab1, 1, 1, 64);
  asm volatile("s_waitcnt vmcnt(4)" ::: "memory");
  __builtin_amdgcn_s_barrier();

  short8 af[4][2], b01[2][2], b23[2][2];
  const int bslot = 2 + (wave_n >> 1);
  const int bro = (wave_n & 1) * 64;

  int cur = 0;
#pragma unroll 1
  for (int t = 0; t < NT; ++t) {
    const unsigned short* Ah = &lds[cur][wave_m][0];
    const unsigned short* Bh = &lds[cur][bslot][0];
    const int k1 = t * 64 + 64, k2 = t * 64 + 128;
#pragma unroll
    for (int mf = 0; mf < 4; mf++)
#pragma unroll
      for (int kk = 0; kk < 2; kk++)
        af[mf][kk] = *(const short8*)(Ah + (mf * 16 + r16) * 64 + (((kk * 4 + q4) ^ sw) * 8));
#pragma unroll
    for (int nf = 0; nf < 2; nf++)
#pragma unroll
      for (int kk = 0; kk < 2; kk++)
        b01[nf][kk] =
            *(const short8*)(Bh + (bro + nf * 16 + r16) * 64 + (((kk * 4 + q4) ^ sw) * 8));
    if (t + 1 < NT) stage(Bb0, cur ^ 1, 2, k1);
    __builtin_amdgcn_s_barrier();
    asm volatile("s_waitcnt lgkmcnt(0)" ::: "memory");
    __builtin_amdgcn_s_setprio(1);
#pragma unroll
    for (int mf = 0; mf < 4; mf++)
#pragma unroll
      for (int nf = 0; nf < 2; nf++)
#pragma unroll
        for (int kk = 0; kk < 2; kk++)
          acc[mf][nf] = MFMA16(af[mf][kk], b01[nf][kk], acc[mf][nf], 0, 0, 0);
    __builtin_amdgcn_s_setprio(0);
    __builtin_amdgcn_s_barrier();
#pragma unroll
    for (int nf = 0; nf < 2; nf++)
#pragma unroll
      for (int kk = 0; kk < 2; kk++)
        b23[nf][kk] =
            *(const short8*)(Bh + (bro + (nf + 2) * 16 + r16) * 64 + (((kk * 4 + q4) ^ sw) * 8));
    if (t + 1 < NT) stage(Bb1, cur ^ 1, 3, k1);
    __builtin_amdgcn_s_barrier();
    asm volatile("s_waitcnt lgkmcnt(0)" ::: "memory");
    __builtin_amdgcn_s_setprio(1);
#pragma unroll
    for (int mf = 0; mf < 4; mf++)
#pragma unroll
      for (int nf = 0; nf < 2; nf++)
#pragma unroll
        for (int kk = 0; kk < 2; kk++)
          acc[mf][nf + 2] = MFMA16(af[mf][kk], b23[nf][kk], acc[mf][nf + 2], 0, 0, 0);
    __builtin_amdgcn_s_setprio(0);
    __builtin_amdgcn_s_barrier();
#pragma unroll
    for (int mf = 0; mf < 4; mf++)
#pragma unroll
      for (int kk = 0; kk < 2; kk++)
        af[mf][kk] =
            *(const short8*)(Ah + ((mf + 4) * 16 + r16) * 64 + (((kk * 4 + q4) ^ sw) * 8));
    __builtin_amdgcn_s_barrier();
    asm volatile("s_waitcnt lgkmcnt(0)" ::: "memory");
    __builtin_amdgcn_s_setprio(1);
#pragma unroll
    for (int mf = 0; mf < 4; mf++)
#pragma unroll
      for (int nf = 0; nf < 2; nf++)
#pragma unroll
        for (int kk = 0; kk < 2; kk++)
          acc[mf + 4][nf] = MFMA16(af[mf][kk], b01[nf][kk], acc[mf + 4][nf], 0, 0, 0);
    __builtin_amdgcn_s_setprio(0);
    __builtin_amdgcn_s_barrier();
    if (t + 2 < NT) {
      stage(Ab0, cur, 0, k2);
      stage(Ab1, cur, 1, k2);
    }
    __builtin_amdgcn_s_barrier();
    __builtin_amdgcn_s_setprio(1);
#pragma unroll
    for (int mf = 0; mf < 4; mf++)
#pragma unroll
      for (int nf = 0; nf < 2; nf++)
#pragma unroll
        for (int kk = 0; kk < 2; kk++)
          acc[mf + 4][nf + 2] = MFMA16(af[mf][kk], b23[nf][kk], acc[mf + 4][nf + 2], 0, 0, 0);
    __builtin_amdgcn_s_setprio(0);
    if (t + 1 < NT) {
      if (t + 2 < NT)
        asm volatile("s_waitcnt vmcnt(4)" ::: "memory");
      else
        asm volatile("s_waitcnt vmcnt(0)" ::: "memory");
    }
    __builtin_amdgcn_s_barrier();
    cur ^= 1;
  }

#pragma unroll
  for (int mf = 0; mf < 8; mf++)
#pragma unroll
    for (int nf = 0; nf < 4; nf++) {
      size_t rbase = row0 + wave_m * 128 + mf * 16 + q4 * 4;
      size_t cc = col0 + wave_n * 64 + nf * 16 + r16;
#pragma unroll
      for (int jj = 0; jj < 4; jj++) {
        if constexpr (sizeof(OutT) == 2)
          Cc[(rbase + jj) * (size_t)N + cc] = f2bf(acc[mf][nf][jj]);
        else
          Cc[(rbase + jj) * (size_t)N + cc] = acc[mf][nf][jj];
      }
    }
}

// ---------------- K rope (bid<8192) + V transpose (rest); Q rope moved into attn ----------
__global__ void ropevt_kv(const unsigned short* __restrict__ qkv, const float* __restrict__ cosp,
                          const float* __restrict__ sinp, unsigned short* __restrict__ Kb,
                          unsigned short* __restrict__ Vt) {
  int bid = blockIdx.x, tid = threadIdx.x;
  if (bid < 8192) {
    int gid = bid * 4 + (tid >> 6);  // 0..32767 = (b,t,kvh)
    int lane = tid & 63;
    int kvh = gid & 3;
    int bt = gid >> 2;
    int t = bt % T_SEQ, b = bt / T_SEQ;
    const unsigned short* src = qkv + (size_t)(b * T_SEQ + t) * 3072 + 2048 + kvh * HD;
    float x1 = bf2f(src[lane]), x2 = bf2f(src[64 + lane]);
    float c = cosp[t * 64 + lane], s = sinp[t * 64 + lane];
    float y1 = x1 * c + x2 * s;
    float y2 = x2 * c - x1 * s;
    float ss = y1 * y1 + y2 * y2;
#pragma unroll
    for (int d = 1; d < 64; d <<= 1) ss += __shfl_xor(ss, d);
    float r = rsqrtf(ss * (1.f / 128.f) + 1e-6f);
    unsigned short* dst = Kb + ((size_t)(b * NKV + kvh) * T_SEQ + t) * HD;
    dst[lane] = f2bf(y1 * r);
    dst[64 + lane] = f2bf(y2 * r);
    return;
  }
  // ---- V transpose: qkv cols [2560+kvh*128+d] -> Vt (B,KVH,D,T) ----
  __shared__ unsigned short tile[32][34];
  int idx = bid - 8192;  // 0..4095
  int xg = idx & 63, rem = idx >> 6;
  int yg = rem & 3, zg = rem >> 2;
  int t0 = xg * 32, d0 = yg * 32;
  int b = zg >> 2, kvh = zg & 3;
  int tx = tid & 31, ty = tid >> 5;
#pragma unroll
  for (int i = 0; i < 4; i++)
    tile[ty + i * 8][tx] =
        qkv[(size_t)(b * T_SEQ + t0 + ty + i * 8) * 3072 + 2560 + kvh * HD + d0 + tx];
  __syncthreads();
#pragma unroll
  for (int i = 0; i < 4; i++)
    Vt[((size_t)(b * NKV + kvh) * HD + d0 + ty + i * 8) * T_SEQ + t0 + tx] = tile[tx][ty + i * 8];
}

// ---------------- flash attention: swapped-operand 32x32 MFMA, Q roped IN-PROLOGUE --------
// Structure identical to r10/r14 (proven 158us) except Q is read raw from the qkv buffer
// and RoPE+RMSNorm applied in-register once per block: pairs (d,d+64) = (qf[i][j],
// qf[i+4][j]) are lane-local; the 128-d norm = 64 in-lane squares + one shfl_xor(32).
// Deletes the 64MB Qb round-trip and 3/4 of the old ropevt kernel.
__global__ __launch_bounds__(256, 2) void attn(const unsigned short* __restrict__ qkv,
                                               const float* __restrict__ cosp,
                                               const float* __restrict__ sinp,
                                               const unsigned short* __restrict__ Kn,
                                               const unsigned short* __restrict__ Vt,
                                               unsigned short* __restrict__ Y) {
  __shared__ alignas(16) unsigned short lK[2][32 * 128];
  __shared__ alignas(16) unsigned short lV[2][128 * 32];

  int lin = blockIdx.x;
  int low3 = lin & 7, rest = lin >> 3;
  int chi = rest >> 6, idx = rest & 63;
  int c = (chi << 3) | low3;  // combo (b,kvh) 0..15, xcd-pinned via c&7
  int b = c >> 2, kvh = c & 3;
  int h = kvh * 4 + (idx >> 4);
  int qt = 15 - (idx & 15);  // heavy blocks first
  int Q0 = qt * 128;

  int lane = threadIdx.x & 63, w = threadIdx.x >> 6;  // 4 waves
  const int q5 = lane & 31, hi = lane >> 5, l7 = lane & 7;
  const int qrow = Q0 + w * 32 + q5;
  const unsigned short* Qraw = qkv + (size_t)(b * T_SEQ + qrow) * 3072 + h * HD;
  const unsigned short* Kp = Kn + (size_t)(b * NKV + kvh) * T_SEQ * HD;
  const unsigned short* Vp = Vt + (size_t)(b * NKV + kvh) * HD * T_SEQ;

  // ---- load raw Q row, RoPE + RMSNorm in-register ----
  short8 qf[8];
#pragma unroll
  for (int i = 0; i < 8; i++) qf[i] = *(const short8*)(Qraw + i * 16 + hi * 8);
  float ssq = 0.f;
#pragma unroll
  for (int i = 0; i < 4; i++) {
    int dbase = i * 16 + hi * 8;  // < 64
    float4 c0 = *(const float4*)(cosp + qrow * 64 + dbase);
    float4 c1 = *(const float4*)(cosp + qrow * 64 + dbase + 4);
    float4 s0 = *(const float4*)(sinp + qrow * 64 + dbase);
    float4 s1 = *(const float4*)(sinp + qrow * 64 + dbase + 4);
    float cc[8] = {c0.x, c0.y, c0.z, c0.w, c1.x, c1.y, c1.z, c1.w};
    float sn[8] = {s0.x, s0.y, s0.z, s0.w, s1.x, s1.y, s1.z, s1.w};
#pragma unroll
    for (int j = 0; j < 8; j++) {
      float x1 = bf2f((unsigned short)qf[i][j]);
      float x2 = bf2f((unsigned short)qf[i + 4][j]);
      float y1 = x1 * cc[j] + x2 * sn[j];
      float y2 = x2 * cc[j] - x1 * sn[j];
      ssq += y1 * y1 + y2 * y2;
      qf[i][j] = (short)f2bf(y1);
      qf[i + 4][j] = (short)f2bf(y2);
    }
  }
  ssq += __shfl_xor(ssq, 32);  // lane^32 holds the complementary 64 d's of the same row
  float rsc = rsqrtf(ssq * (1.f / 128.f) + 1e-6f) * 0.08838834764831845f;  // *1/sqrt(128)
#pragma unroll
  for (int i = 0; i < 8; i++)
#pragma unroll
    for (int j = 0; j < 8; j++)
      qf[i][j] = (short)f2bf(bf2f((unsigned short)qf[i][j]) * rsc);

  f32x16 o4[4];
#pragma unroll
  for (int d = 0; d < 4; d++)
#pragma unroll
    for (int r = 0; r < 16; r++) o4[d][r] = 0.f;
  float mrow = -1e30f, Lp = 0.f;

  auto stageK = [&](int kv0, int buf) {
#pragma unroll
    for (int j = 0; j < 2; ++j) {
      int cw = w * 2 + j;
      int row = cw * 4 + (lane >> 4);
      int cb = lane & 15;
      gload_lds16(Kp + (size_t)(kv0 + row) * HD + ((cb ^ (row & 7)) * 8), &lK[buf][cw * 512]);
    }
  };
  auto stageV = [&](int kv0, int buf) {
#pragma unroll
    for (int j = 0; j < 2; ++j) {
      int cw = w * 2 + j;
      int row = cw * 16 + (lane >> 2);
      int ts = lane & 3;
      gload_lds16(Vp + (size_t)row * T_SEQ + kv0 + ((ts ^ (row & 3)) * 8), &lV[buf][cw * 512]);
    }
  };

  const int ntiles = 4 * qt + 4;
  const int ntw = (Q0 + w * 32 + 63) >> 5;

  stageK(0, 0);
  stageV(0, 0);
  __syncthreads();
  int cur = 0;

  for (int t = 0; t < ntiles; ++t) {
    int kv0 = t * 32;
    if (t + 1 < ntiles) { stageK(kv0 + 32, cur ^ 1); stageV(kv0 + 32, cur ^ 1); }
    if (t < ntw) {
      f32x16 st;
#pragma unroll
      for (int r = 0; r < 16; r++) st[r] = 0.f;
      __builtin_amdgcn_s_setprio(1);
#pragma unroll
      for (int i = 0; i < 8; i++) {
        short8 kf = *(const short8*)(&lK[cur][q5 * 128 + (((2 * i + hi) ^ l7) * 8)]);
        st = MFMA32(kf, qf[i], st, 0, 0, 0);
      }
      __builtin_amdgcn_s_setprio(0);
      if (kv0 + 31 > Q0 + w * 32) {
#pragma unroll
        for (int r = 0; r < 16; r++) {
          int kg = kv0 + (r & 3) + 8 * (r >> 2) + 4 * hi;
          if (kg > qrow) st[r] = -1e30f;
        }
      }
      float pm = st[0];
#pragma unroll
      for (int r = 1; r < 16; r++) pm = fmaxf(pm, st[r]);
      pm = fmaxf(pm, __shfl_xor(pm, 32));
      if (!__all(pm - mrow <= 8.0f)) {
        float mn = fmaxf(mrow, pm);
        float al = __expf(mrow - mn);
        mrow = mn;
        Lp *= al;
#pragma unroll
        for (int d = 0; d < 4; d++)
#pragma unroll
          for (int r = 0; r < 16; r++) o4[d][r] *= al;
      }
      float p[16];
#pragma unroll
      for (int r = 0; r < 16; r++) {
        p[r] = __expf(st[r] - mrow);
        Lp += p[r];
      }
#pragma unroll
      for (int ks = 0; ks < 2; ks++) {
        unsigned x0 = pkbf(p[8 * ks + 0], p[8 * ks + 1]);
        unsigned x1 = pkbf(p[8 * ks + 2], p[8 * ks + 3]);
        unsigned y0 = pkbf(p[8 * ks + 4], p[8 * ks + 5]);
        unsigned y1 = pkbf(p[8 * ks + 6], p[8 * ks + 7]);
        unsigned sx0 = __shfl_xor((int)x0, 32), sx1 = __shfl_xor((int)x1, 32);
        unsigned sy0 = __shfl_xor((int)y0, 32), sy1 = __shfl_xor((int)y1, 32);
        union { unsigned u[4]; short8 s; } pw;
        pw.u[0] = hi ? sy0 : x0;
        pw.u[1] = hi ? sy1 : x1;
        pw.u[2] = hi ? y0 : sx0;
        pw.u[3] = hi ? y1 : sx1;
        const int cb = 2 * ks + hi;
        __builtin_amdgcn_s_setprio(1);
#pragma unroll
        for (int db = 0; db < 4; db++) {
          int vrow = db * 32 + q5;
          short8 vf = *(const short8*)(&lV[cur][vrow * 32 + ((cb ^ (vrow & 3)) * 8)]);
          o4[db] = MFMA32(vf, pw.s, o4[db], 0, 0, 0);
        }
        __builtin_amdgcn_s_setprio(0);
      }
    }
    __syncthreads();
    cur ^= 1;
  }

  float L = Lp + __shfl_xor(Lp, 32);
  float linv = 1.f / L;
  unsigned short* Yp = Y + ((size_t)(b * T_SEQ) + qrow) * (NH * HD) + h * HD;
#pragma unroll
  for (int db = 0; db < 4; db++)
#pragma unroll
    for (int g = 0; g < 4; g++) {
      int d0 = db * 32 + g * 8 + 4 * hi;
      ushort4 v = make_ushort4(f2bf(o4[db][g * 4 + 0] * linv), f2bf(o4[db][g * 4 + 1] * linv),
                               f2bf(o4[db][g * 4 + 2] * linv), f2bf(o4[db][g * 4 + 3] * linv));
      *(ushort4*)(Yp + d0) = v;
    }
}

extern "C" void kernel_launch(void* const* d_in, const int* in_sizes, int n_in,
                              void* d_out, int out_size, void* d_ws, size_t ws_size,
                              hipStream_t stream) {
  const float* x = (const float*)d_in[0];
  const float* cosp = (const float*)d_in[1];
  const float* sinp = (const float*)d_in[2];
  const float* Wq = (const float*)d_in[3];
  const float* Wk = (const float*)d_in[4];
  const float* Wv = (const float*)d_in[5];
  const float* Wo = (const float*)d_in[6];
  float* out = (float*)d_out;

  char* ws = (char*)d_ws;
  size_t off = 0;
  auto alloc = [&](size_t bytes) { void* p = ws + off; off += bytes; return p; };
  const size_t BT = (size_t)B_SZ * T_SEQ;  // 8192
  unsigned short* xb = (unsigned short*)alloc(BT * C_DIM * 2);              // 32MB
  unsigned short* WqkvT = (unsigned short*)alloc((size_t)3072 * 2048 * 2);  // 12.6MB
  unsigned short* WoT = (unsigned short*)alloc((size_t)2048 * 2048 * 2);    // 8.4MB
  unsigned short* qkv = (unsigned short*)alloc(BT * 3072 * 2);              // 48MB (live thru attn)
  unsigned short* Kb = (unsigned short*)alloc(BT * 512 * 2);                // 8MB
  unsigned short* Vb = (unsigned short*)alloc(BT * 512 * 2);                // 8MB
  unsigned short* Yb = xb;  // alias: xb dead after gemm128 (qkv must stay live for attn Q)

  prep<<<26624, 256, 0, stream>>>(x, xb, Wq, Wk, Wv, Wo, WqkvT, WoT);

  gemm128<unsigned short><<<768, 512, 0, stream>>>(xb, WqkvT, qkv, 3072, 2048, 64);

  ropevt_kv<<<12288, 256, 0, stream>>>(qkv, cosp, sinp, Kb, Vb);

  attn<<<dim3(1024), 256, 0, stream>>>(qkv, cosp, sinp, Kb, Vb, Yb);

  gemm256<float><<<256, 512, 0, stream>>>(Yb, WoT, out, 2048, 2048, 32);
}